// Round 3
// baseline (1069.918 us; speedup 1.0000x reference)
//
#include <hip/hip_runtime.h>
#include <hip/hip_bf16.h>
#include <math.h>

#define NN 6144
#define FIN 256
#define HID 64

// All inputs and outputs are float32 (reference dtypes). d_out is float*.

// ---------- hxw = x @ W1 (fp64 accumulate; feeds decision-critical chain) ----------
__global__ __launch_bounds__(256) void k_hxw(const float* __restrict__ x,
                                             const float* __restrict__ W1,
                                             double* __restrict__ hxw) {
  int t = blockIdx.x * 256 + threadIdx.x;   // exactly N*64 threads
  int i = t >> 6, c = t & 63;
  const float* xr = x + (size_t)i * FIN;
  double a = 0.0;
#pragma unroll 8
  for (int k = 0; k < FIN; ++k)
    a = fma((double)xr[k], (double)W1[k * HID + c], a);
  hxw[t] = a;
}

// ---------- degree count + adj_orig scatter ----------
__global__ __launch_bounds__(256) void k_edges(const int* __restrict__ ei, int E,
                                               int* __restrict__ deg,
                                               float* __restrict__ adjO) {
  int e = blockIdx.x * 256 + threadIdx.x;
  if (e >= E) return;
  int s = ei[e], d = ei[E + e];
  atomicAdd(&deg[d], 1);
  adjO[(size_t)s * NN + d] = 1.0f;
}

__global__ __launch_bounds__(256) void k_dinv(const int* __restrict__ deg,
                                              double* __restrict__ dinv) {
  int i = blockIdx.x * 256 + threadIdx.x;
  if (i < NN) dinv[i] = 1.0 / sqrt((double)(deg[i] + 1));  // +1: self-loop
}

// ---------- GCN edge aggregation (fp64 atomics) ----------
__global__ __launch_bounds__(256) void k_agg(const int* __restrict__ ei, int E,
                                             const double* __restrict__ hxw,
                                             const double* __restrict__ dinv,
                                             double* __restrict__ hagg) {
  int t = blockIdx.x * 256 + threadIdx.x;
  if (t >= E * HID) return;
  int e = t >> 6, c = t & 63;
  int s = ei[e], d = ei[E + e];
  atomicAdd(&hagg[(size_t)d * HID + c], hxw[(size_t)s * HID + c] * (dinv[s] * dinv[d]));
}

// ---------- self-loop term + bias ----------
__global__ __launch_bounds__(256) void k_selfbias(const double* __restrict__ hxw,
                                                  const double* __restrict__ dinv,
                                                  const float* __restrict__ b1,
                                                  double* __restrict__ hagg) {
  int t = blockIdx.x * 256 + threadIdx.x;
  int i = t >> 6, c = t & 63;
  hagg[t] += hxw[t] * dinv[i] * dinv[i] + (double)b1[c];
}

// ---------- Lmax = max_i ||h_i||^2 (== global max of h h^T by Cauchy-Schwarz) ----------
// Same sequential fma chain order (c ascending) as k_tile's diagonal accumulation -> bitwise match.
__global__ __launch_bounds__(256) void k_lmax(const double* __restrict__ h,
                                              unsigned long long* __restrict__ lmax) {
  __shared__ double red[256];
  int i = blockIdx.x * 256 + threadIdx.x;
  const double* hr = h + (size_t)i * HID;
  double s = 0.0;
  for (int c = 0; c < HID; ++c) s = fma(hr[c], hr[c], s);
  red[threadIdx.x] = s;
  __syncthreads();
  for (int w = 128; w > 0; w >>= 1) {
    if (threadIdx.x < w) {
      double o = red[threadIdx.x + w];
      if (o > red[threadIdx.x]) red[threadIdx.x] = o;
    }
    __syncthreads();
  }
  if (threadIdx.x == 0)
    atomicMax(lmax, (unsigned long long)__double_as_longlong(red[0]));  // vals > 0: bits monotone
}

// ---------- big fused N^2 kernel: L = h h^T tile, adj_logits + straight-through sample ----------
// round(sigmoid(logit(p)+logit(u))) == (p > 1-u): logit strictly monotone, tie -> 0 (round-half-even).
// Grid (96,96); blocks with J<I exit; block (I,J), I<J also writes mirrored (J,I) tiles via LDS transpose.
// LDS: Ls/Ss (f32 mirror tiles) alias the dead As/Bs staging after the acc loop (sync in between).
__global__ __launch_bounds__(256) void k_tile(const double* __restrict__ h,
                                              const unsigned long long* __restrict__ lmaxp,
                                              const float* __restrict__ u,
                                              const float* __restrict__ adjO,
                                              float* __restrict__ adjL,
                                              float* __restrict__ adjS) {
  int I = blockIdx.y, J = blockIdx.x;
  if (J < I) return;
  __shared__ double smem[2 * 64 * 33];            // 33,792 B
  double* As = smem;                              // stride 33 kills bank conflicts
  double* Bs = smem + 64 * 33;
  float* Ls = (float*)smem;                       // 64*65 f32 (16,640 B), aliases As
  float* Ss = ((float*)smem) + 64 * 65;           // 64*65 f32, aliases As/Bs
  int t = threadIdx.x;
  int tx = t & 15, ty = t >> 4;
  double acc[4][4];
#pragma unroll
  for (int p = 0; p < 4; ++p)
#pragma unroll
    for (int q = 0; q < 4; ++q) acc[p][q] = 0.0;
  const double* hI = h + (size_t)I * 64 * HID;
  const double* hJ = h + (size_t)J * 64 * HID;
  for (int k0 = 0; k0 < 64; k0 += 32) {
    __syncthreads();
    for (int idx = t; idx < 2048; idx += 256) {
      int r = idx >> 5, k = idx & 31;
      As[r * 33 + k] = hI[r * 64 + k0 + k];
      Bs[r * 33 + k] = hJ[r * 64 + k0 + k];
    }
    __syncthreads();
#pragma unroll 8
    for (int k = 0; k < 32; ++k) {
      double a0 = As[ty * 33 + k], a1 = As[(ty + 16) * 33 + k];
      double a2 = As[(ty + 32) * 33 + k], a3 = As[(ty + 48) * 33 + k];
      double c0 = Bs[tx * 33 + k], c1 = Bs[(tx + 16) * 33 + k];
      double c2 = Bs[(tx + 32) * 33 + k], c3 = Bs[(tx + 48) * 33 + k];
      acc[0][0] = fma(a0, c0, acc[0][0]); acc[0][1] = fma(a0, c1, acc[0][1]);
      acc[0][2] = fma(a0, c2, acc[0][2]); acc[0][3] = fma(a0, c3, acc[0][3]);
      acc[1][0] = fma(a1, c0, acc[1][0]); acc[1][1] = fma(a1, c1, acc[1][1]);
      acc[1][2] = fma(a1, c2, acc[1][2]); acc[1][3] = fma(a1, c3, acc[1][3]);
      acc[2][0] = fma(a2, c0, acc[2][0]); acc[2][1] = fma(a2, c1, acc[2][1]);
      acc[2][2] = fma(a2, c2, acc[2][2]); acc[2][3] = fma(a2, c3, acc[2][3]);
      acc[3][0] = fma(a3, c0, acc[3][0]); acc[3][1] = fma(a3, c1, acc[3][1]);
      acc[3][2] = fma(a3, c2, acc[3][2]); acc[3][3] = fma(a3, c3, acc[3][3]);
    }
  }
  __syncthreads();  // As/Bs dead from here; Ls/Ss may overwrite
  double Lmax = __longlong_as_double((long long)(*lmaxp));
  bool diag = (I == J);
#pragma unroll
  for (int p = 0; p < 4; ++p) {
#pragma unroll
    for (int q = 0; q < 4; ++q) {
      int r = ty + 16 * p, c = tx + 16 * q;
      int gi = I * 64 + r, gj = J * 64 + c;
      double L = acc[p][q];
      float lf = (float)L;
      adjL[(size_t)gi * NN + gj] = lf;
      float stv;
      if (diag && r == c) {
        stv = 1.0f;  // fill_diagonal_(1)
      } else {
        // only the upper-triangle (a<b) entry decides; L[a,b]==L[b,a] bitwise
        size_t ab = (gi < gj) ? ((size_t)gi * NN + gj) : ((size_t)gj * NN + gi);
        double ao = (double)adjO[ab];
        double uu = (double)u[ab];
        double ep = 0.8 * (L / Lmax) + 0.2 * ao;
        if (ep < 0.0) ep = 0.0;
        double pl = ep;
        if (pl < 1e-6) pl = 1e-6;
        double hi = 1.0 - 1e-6;
        if (pl > hi) pl = hi;
        stv = (pl > 1.0 - uu) ? 1.0f : 0.0f;  // == round(sigmoid(logit(pl)+logit(uu)))
      }
      adjS[(size_t)gi * NN + gj] = stv;
      if (!diag) {
        Ls[c * 65 + r] = lf;   // store transposed for mirror tile
        Ss[c * 65 + r] = stv;
      }
    }
  }
  if (!diag) {
    __syncthreads();
    for (int idx = t; idx < 4096; idx += 256) {
      int a = idx >> 6, b = idx & 63;
      size_t off = (size_t)(J * 64 + a) * NN + (I * 64 + b);
      adjL[off] = Ls[a * 65 + b];
      adjS[off] = Ss[a * 65 + b];
    }
  }
}

// ---------- row sums of adj_sampled -> dinv2 = rsqrt(rowsum + 1) (the +eye in A) ----------
__global__ __launch_bounds__(256) void k_rowsum(const float* __restrict__ adjS,
                                                double* __restrict__ dinv2) {
  __shared__ int red[256];
  int i = blockIdx.x;
  int cnt = 0;
  for (int j = threadIdx.x; j < NN; j += 256)
    cnt += (adjS[(size_t)i * NN + j] > 0.5f) ? 1 : 0;
  red[threadIdx.x] = cnt;
  __syncthreads();
  for (int w = 128; w > 0; w >>= 1) {
    if (threadIdx.x < w) red[threadIdx.x] += red[threadIdx.x + w];
    __syncthreads();
  }
  if (threadIdx.x == 0) dinv2[i] = 1.0 / sqrt((double)(red[0] + 1));
}

// ---------- g[j,c] = dinv2[j] * hxw[j,c] (fp32 for the continuous path) ----------
__global__ __launch_bounds__(256) void k_gscale(const double* __restrict__ hv,
                                                const double* __restrict__ dinv2,
                                                float* __restrict__ g) {
  int t = blockIdx.x * 256 + threadIdx.x;
  int j = t >> 6;
  g[t] = (float)(dinv2[j] * hv[t]);
}

// ---------- dense An-matmul partial: slice s sums j in [s*768, (s+1)*768) ----------
__global__ __launch_bounds__(256) void k_anmm(const float* __restrict__ adjS,
                                              const float* __restrict__ g,
                                              float* __restrict__ accb) {
  int I = blockIdx.x;  // 0..95 row block
  int s = blockIdx.y;  // 0..7 split-K slice
  __shared__ float as[64 * 65];
  __shared__ float gs[64 * 64];
  int t = threadIdx.x, tx = t & 15, ty = t >> 4;
  float acc[4][4];
#pragma unroll
  for (int p = 0; p < 4; ++p)
#pragma unroll
    for (int q = 0; q < 4; ++q) acc[p][q] = 0.0f;
  for (int Jt = s * 12; Jt < (s + 1) * 12; ++Jt) {
    __syncthreads();
    for (int idx = t; idx < 4096; idx += 256) {
      int r = idx >> 6, cc = idx & 63;
      as[r * 65 + cc] = adjS[(size_t)(I * 64 + r) * NN + Jt * 64 + cc];
      gs[idx] = g[(size_t)(Jt * 64 + r) * HID + cc];
    }
    __syncthreads();
#pragma unroll 4
    for (int j = 0; j < 64; ++j) {
      float c0 = gs[j * 64 + tx], c1 = gs[j * 64 + tx + 16];
      float c2 = gs[j * 64 + tx + 32], c3 = gs[j * 64 + tx + 48];
      float a0 = as[ty * 65 + j], a1 = as[(ty + 16) * 65 + j];
      float a2 = as[(ty + 32) * 65 + j], a3 = as[(ty + 48) * 65 + j];
      acc[0][0] = fmaf(a0, c0, acc[0][0]); acc[0][1] = fmaf(a0, c1, acc[0][1]);
      acc[0][2] = fmaf(a0, c2, acc[0][2]); acc[0][3] = fmaf(a0, c3, acc[0][3]);
      acc[1][0] = fmaf(a1, c0, acc[1][0]); acc[1][1] = fmaf(a1, c1, acc[1][1]);
      acc[1][2] = fmaf(a1, c2, acc[1][2]); acc[1][3] = fmaf(a1, c3, acc[1][3]);
      acc[2][0] = fmaf(a2, c0, acc[2][0]); acc[2][1] = fmaf(a2, c1, acc[2][1]);
      acc[2][2] = fmaf(a2, c2, acc[2][2]); acc[2][3] = fmaf(a2, c3, acc[2][3]);
      acc[3][0] = fmaf(a3, c0, acc[3][0]); acc[3][1] = fmaf(a3, c1, acc[3][1]);
      acc[3][2] = fmaf(a3, c2, acc[3][2]); acc[3][3] = fmaf(a3, c3, acc[3][3]);
    }
  }
  float* out = accb + (size_t)s * NN * HID;
#pragma unroll
  for (int p = 0; p < 4; ++p)
#pragma unroll
    for (int q = 0; q < 4; ++q)
      out[(size_t)(I * 64 + ty + 16 * p) * HID + tx + 16 * q] = acc[p][q];
}

// ---------- epilogue 1: x1 = dinv2_i*(sum + g_i) + b1; z = PReLU(x1) ----------
__global__ __launch_bounds__(256) void k_ep1(const float* __restrict__ accb,
                                             const float* __restrict__ g,
                                             const double* __restrict__ dinv2,
                                             const float* __restrict__ b1,
                                             const float* __restrict__ prelu,
                                             float* __restrict__ x1,
                                             float* __restrict__ zout) {
  int t = blockIdx.x * 256 + threadIdx.x;
  int i = t >> 6, c = t & 63;
  double ss = 0.0;
  for (int s = 0; s < 8; ++s) ss += (double)accb[(size_t)s * NN * HID + t];
  float v = (float)(dinv2[i] * (ss + (double)g[t])) + b1[c];
  x1[t] = v;
  float pa = prelu[0];
  zout[t] = v >= 0.0f ? v : pa * v;
}

// ---------- BN stats (biased var, training mode) ----------
__global__ __launch_bounds__(256) void k_bnstats(const float* __restrict__ x1,
                                                 double* __restrict__ meanv,
                                                 double* __restrict__ istd) {
  __shared__ double r1[256], r2[256];
  int c = blockIdx.x;
  double s1 = 0.0, s2 = 0.0;
  for (int i = threadIdx.x; i < NN; i += 256) {
    double v = (double)x1[(size_t)i * HID + c];
    s1 += v;
    s2 += v * v;
  }
  r1[threadIdx.x] = s1;
  r2[threadIdx.x] = s2;
  __syncthreads();
  for (int w = 128; w > 0; w >>= 1) {
    if (threadIdx.x < w) {
      r1[threadIdx.x] += r1[threadIdx.x + w];
      r2[threadIdx.x] += r2[threadIdx.x + w];
    }
    __syncthreads();
  }
  if (threadIdx.x == 0) {
    double m = r1[0] / (double)NN;
    double var = r2[0] / (double)NN - m * m;
    meanv[c] = m;
    istd[c] = 1.0 / sqrt(var + 1e-5);
  }
}

// ---------- BN apply + ReLU ----------
__global__ __launch_bounds__(256) void k_xr(const float* __restrict__ x1,
                                            const double* __restrict__ meanv,
                                            const double* __restrict__ istd,
                                            const float* __restrict__ gamma,
                                            const float* __restrict__ beta,
                                            float* __restrict__ xr) {
  int t = blockIdx.x * 256 + threadIdx.x;
  int c = t & 63;
  float v = gamma[c] * (float)(((double)x1[t] - meanv[c]) * istd[c]) + beta[c];
  xr[t] = v > 0.0f ? v : 0.0f;
}

// ---------- y = xr @ W2; g2 = dinv2 * y ----------
__global__ __launch_bounds__(256) void k_y_g2(const float* __restrict__ xr,
                                              const float* __restrict__ W2,
                                              const double* __restrict__ dinv2,
                                              float* __restrict__ g2) {
  int t = blockIdx.x * 256 + threadIdx.x;
  int j = t >> 6, c = t & 63;
  const float* xrow = xr + (size_t)j * HID;
  float a = 0.0f;
#pragma unroll 8
  for (int k = 0; k < HID; ++k) a = fmaf(xrow[k], W2[k * HID + c], a);
  g2[t] = (float)(dinv2[j] * (double)a);
}

// ---------- epilogue 2: x2 = dinv2_i*(sum + g2_i) + b2 ----------
__global__ __launch_bounds__(256) void k_ep2(const float* __restrict__ accb,
                                             const float* __restrict__ g2,
                                             const double* __restrict__ dinv2,
                                             const float* __restrict__ b2p,
                                             float* __restrict__ x2out) {
  int t = blockIdx.x * 256 + threadIdx.x;
  int i = t >> 6, c = t & 63;
  double ss = 0.0;
  for (int s = 0; s < 8; ++s) ss += (double)accb[(size_t)s * NN * HID + t];
  x2out[t] = (float)(dinv2[i] * (ss + (double)g2[t])) + b2p[c];
}

extern "C" void kernel_launch(void* const* d_in, const int* in_sizes, int n_in,
                              void* d_out, int out_size, void* d_ws, size_t ws_size,
                              hipStream_t stream) {
  const float* x = (const float*)d_in[0];
  const int* ei = (const int*)d_in[1];
  const float* W1 = (const float*)d_in[2];
  const float* b1 = (const float*)d_in[3];
  const float* W2 = (const float*)d_in[4];
  const float* b2 = (const float*)d_in[5];
  const float* gamma = (const float*)d_in[6];
  const float* beta = (const float*)d_in[7];
  const float* prelu = (const float*)d_in[8];
  const float* u = (const float*)d_in[9];
  int E = in_sizes[1] / 2;

  float* out = (float*)d_out;
  float* o_x2 = out;
  float* o_z = out + (size_t)NN * HID;
  float* o_adjS = out + (size_t)2 * NN * HID;
  float* o_adjL = o_adjS + (size_t)NN * NN;
  float* o_adjO = o_adjL + (size_t)NN * NN;

  // workspace layout: region A (phase-1, later overlaid by accb), region B persistent
  char* w = (char*)d_ws;
  double* hxw = (double*)w;                        // 3,145,728 B
  double* hagg = (double*)(w + 3145728);           // 3,145,728 B
  double* dinv = (double*)(w + 6291456);           // 49,152 B
  int* deg = (int*)(w + 6340608);                  // 24,576 B
  float* accb = (float*)w;                         // 12,582,912 B, overlays dead region A
  double* dinv2 = (double*)(w + 12582912);         // 49,152 B
  unsigned long long* lmax = (unsigned long long*)(w + 12632064);  // 8 B
  double* meanv = (double*)(w + 12632128);         // 512 B
  double* istd = (double*)(w + 12632640);          // 512 B
  float* x1 = (float*)(w + 12633152);              // 1,572,864 B
  float* gg = (float*)(w + 14206016);              // 1,572,864 B
  float* xr = (float*)(w + 15778880);              // 1,572,864 B
  float* g2 = (float*)(w + 17351744);              // 1,572,864 B  -> total 18,924,608 B

  hipMemsetAsync(deg, 0, NN * sizeof(int), stream);
  hipMemsetAsync(hagg, 0, (size_t)NN * HID * sizeof(double), stream);
  hipMemsetAsync(lmax, 0, sizeof(unsigned long long), stream);
  hipMemsetAsync(o_adjO, 0, (size_t)NN * NN * sizeof(float), stream);

  k_hxw<<<NN * HID / 256, 256, 0, stream>>>(x, W1, hxw);
  k_edges<<<(E + 255) / 256, 256, 0, stream>>>(ei, E, deg, o_adjO);
  k_dinv<<<NN / 256, 256, 0, stream>>>(deg, dinv);
  k_agg<<<(E * HID + 255) / 256, 256, 0, stream>>>(ei, E, hxw, dinv, hagg);
  k_selfbias<<<NN * HID / 256, 256, 0, stream>>>(hxw, dinv, b1, hagg);
  k_lmax<<<NN / 256, 256, 0, stream>>>(hagg, lmax);
  dim3 gt(96, 96);
  k_tile<<<gt, 256, 0, stream>>>(hagg, lmax, u, o_adjO, o_adjL, o_adjS);
  k_rowsum<<<NN, 256, 0, stream>>>(o_adjS, dinv2);
  k_gscale<<<NN * HID / 256, 256, 0, stream>>>(hxw, dinv2, gg);
  dim3 ga(96, 8);
  k_anmm<<<ga, 256, 0, stream>>>(o_adjS, gg, accb);
  k_ep1<<<NN * HID / 256, 256, 0, stream>>>(accb, gg, dinv2, b1, prelu, x1, o_z);
  k_bnstats<<<HID, 256, 0, stream>>>(x1, meanv, istd);
  k_xr<<<NN * HID / 256, 256, 0, stream>>>(x1, meanv, istd, gamma, beta, xr);
  k_y_g2<<<NN * HID / 256, 256, 0, stream>>>(xr, W2, dinv2, g2);
  k_anmm<<<ga, 256, 0, stream>>>(o_adjS, g2, accb);
  k_ep2<<<NN * HID / 256, 256, 0, stream>>>(accb, g2, dinv2, b2, o_x2);
}